// Round 1
// baseline (903.667 us; speedup 1.0000x reference)
//
#include <hip/hip_runtime.h>
#include <math.h>

// GCN 2-layer: conv1(x) -> BN -> ReLU -> conv2
// conv(x) = Dinv^1/2 (A+I) Dinv^1/2 (x W) + b, built as:
//   h = x @ W (dense GEMM, K=128)
//   agg[i] = dinv[i]^2 * h[i] + sum_{e: dst=i} dinv[src]*dinv[i]*h[src] + b
// CSR by dst built on-device each call (count -> scan -> atomic fill).

static constexpr int KDIM = 128;

// ---------------- setup kernels ----------------

__global__ void zero_kernel(int* __restrict__ cnt, int n, float* __restrict__ bnacc) {
  int i = blockIdx.x * blockDim.x + threadIdx.x;
  if (i < n) cnt[i] = 0;
  if (i < 256) bnacc[i] = 0.f;
}

__global__ void count_kernel(const int* __restrict__ dst, int E, int* __restrict__ cnt) {
  int i = blockIdx.x * blockDim.x + threadIdx.x;
  if (i < E) atomicAdd(&cnt[dst[i]], 1);
}

// phase 1: per-block (256-wide) sums of cnt
__global__ void scan1_kernel(const int* __restrict__ cnt, int n, int* __restrict__ bsum) {
  __shared__ int sh[256];
  int i = blockIdx.x * 256 + threadIdx.x;
  sh[threadIdx.x] = (i < n) ? cnt[i] : 0;
  __syncthreads();
  for (int o = 128; o > 0; o >>= 1) {
    if (threadIdx.x < o) sh[threadIdx.x] += sh[threadIdx.x + o];
    __syncthreads();
  }
  if (threadIdx.x == 0) bsum[blockIdx.x] = sh[0];
}

// phase 2: exclusive scan of block sums (requires nb <= 512; nb=391 here)
__global__ void scan2_kernel(int* __restrict__ bsum, int nb) {
  __shared__ int sh[512];
  int v = (threadIdx.x < nb) ? bsum[threadIdx.x] : 0;
  sh[threadIdx.x] = v;
  __syncthreads();
  for (int o = 1; o < 512; o <<= 1) {
    int t = (threadIdx.x >= o) ? sh[threadIdx.x - o] : 0;
    __syncthreads();
    sh[threadIdx.x] += t;
    __syncthreads();
  }
  if (threadIdx.x < nb) bsum[threadIdx.x] = sh[threadIdx.x] - v;  // exclusive
}

// phase 3: per-element exclusive scan + dinv + cursor init
__global__ void scan3_kernel(const int* __restrict__ cnt, int n,
                             const int* __restrict__ bsum,
                             int* __restrict__ off, int* __restrict__ cur,
                             float* __restrict__ dinv, int E) {
  __shared__ int sh[256];
  int i = blockIdx.x * 256 + threadIdx.x;
  int v = (i < n) ? cnt[i] : 0;
  sh[threadIdx.x] = v;
  __syncthreads();
  for (int o = 1; o < 256; o <<= 1) {
    int t = (threadIdx.x >= o) ? sh[threadIdx.x - o] : 0;
    __syncthreads();
    sh[threadIdx.x] += t;
    __syncthreads();
  }
  if (i < n) {
    int excl = bsum[blockIdx.x] + sh[threadIdx.x] - v;
    off[i] = excl;
    cur[i] = excl;
    dinv[i] = rsqrtf((float)(v + 1));  // +1 self-loop
  }
  if (i == 0) off[n] = E;
}

__global__ void fill_kernel(const int* __restrict__ src, const int* __restrict__ dst,
                            int E, int* __restrict__ cur, int* __restrict__ csr) {
  int i = blockIdx.x * blockDim.x + threadIdx.x;
  if (i < E) {
    int p = atomicAdd(&cur[dst[i]], 1);
    csr[p] = src[i];
  }
}

// ---------------- GEMM: C[M x N] = A[M x 128] @ B[128 x N] ----------------
// BM=64, BN(tile)=64, BK=64, 256 threads, 4x4 micro-tile.
// FUSE: apply y = relu(a*scale[k]+shift[k]) on A-load (BN+ReLU fused into GEMM2).
template <bool FUSE>
__global__ __launch_bounds__(256) void gemm_kernel(
    const float* __restrict__ A, const float* __restrict__ B, float* __restrict__ C,
    int M, int N, const float* __restrict__ scale, const float* __restrict__ shift) {
  constexpr int BM = 64, BN = 64, BK = 64;
  __shared__ float As[BM][BK + 4];
  __shared__ float Bs[BK][BN + 4];
  const int tid = threadIdx.x;
  const int tx = tid & 15, ty = tid >> 4;
  const int brow = blockIdx.x * BM;
  const int bcol = blockIdx.y * BN;
  float acc[4][4] = {{0.f}};

  for (int kb = 0; kb < KDIM; kb += BK) {
    // A tile: 64x64 floats = 4 float4 per thread, coalesced, row-major in LDS
#pragma unroll
    for (int p = 0; p < 4; ++p) {
      int f = tid + p * 256;
      int r = f >> 4;
      int kq = (f & 15) << 2;
      float4 v = make_float4(0.f, 0.f, 0.f, 0.f);
      int gr = brow + r;
      if (gr < M) {
        v = *reinterpret_cast<const float4*>(&A[gr * KDIM + kb + kq]);
        if (FUSE) {
          int c = kb + kq;
          v.x = fmaxf(v.x * scale[c + 0] + shift[c + 0], 0.f);
          v.y = fmaxf(v.y * scale[c + 1] + shift[c + 1], 0.f);
          v.z = fmaxf(v.z * scale[c + 2] + shift[c + 2], 0.f);
          v.w = fmaxf(v.w * scale[c + 3] + shift[c + 3], 0.f);
        }
      }
      *reinterpret_cast<float4*>(&As[r][kq]) = v;
    }
    // B tile: 64x64 floats
#pragma unroll
    for (int p = 0; p < 4; ++p) {
      int f = tid + p * 256;
      int r = f >> 4;
      int nq = (f & 15) << 2;
      float4 v = *reinterpret_cast<const float4*>(&B[(kb + r) * N + bcol + nq]);
      *reinterpret_cast<float4*>(&Bs[r][nq]) = v;
    }
    __syncthreads();
#pragma unroll 16
    for (int kk = 0; kk < BK; ++kk) {
      float a0 = As[ty * 4 + 0][kk];
      float a1 = As[ty * 4 + 1][kk];
      float a2 = As[ty * 4 + 2][kk];
      float a3 = As[ty * 4 + 3][kk];
      float4 b = *reinterpret_cast<const float4*>(&Bs[kk][tx * 4]);
      acc[0][0] = fmaf(a0, b.x, acc[0][0]); acc[0][1] = fmaf(a0, b.y, acc[0][1]);
      acc[0][2] = fmaf(a0, b.z, acc[0][2]); acc[0][3] = fmaf(a0, b.w, acc[0][3]);
      acc[1][0] = fmaf(a1, b.x, acc[1][0]); acc[1][1] = fmaf(a1, b.y, acc[1][1]);
      acc[1][2] = fmaf(a1, b.z, acc[1][2]); acc[1][3] = fmaf(a1, b.w, acc[1][3]);
      acc[2][0] = fmaf(a2, b.x, acc[2][0]); acc[2][1] = fmaf(a2, b.y, acc[2][1]);
      acc[2][2] = fmaf(a2, b.z, acc[2][2]); acc[2][3] = fmaf(a2, b.w, acc[2][3]);
      acc[3][0] = fmaf(a3, b.x, acc[3][0]); acc[3][1] = fmaf(a3, b.y, acc[3][1]);
      acc[3][2] = fmaf(a3, b.z, acc[3][2]); acc[3][3] = fmaf(a3, b.w, acc[3][3]);
    }
    __syncthreads();
  }
#pragma unroll
  for (int i = 0; i < 4; ++i) {
    int gr = brow + ty * 4 + i;
    if (gr < M) {
      *reinterpret_cast<float4*>(&C[gr * N + bcol + tx * 4]) =
          make_float4(acc[i][0], acc[i][1], acc[i][2], acc[i][3]);
    }
  }
}

// ---------------- aggregation: out[i] = dinv[i]^2*h[i] + sum_e w*h[src] + bias ----------------
template <int W>
__global__ void agg_kernel(const float* __restrict__ h, const float* __restrict__ dinv,
                           const int* __restrict__ off, const int* __restrict__ csr,
                           const float* __restrict__ bias, float* __restrict__ out, int n) {
  const int i = blockIdx.x;
  const int t = threadIdx.x;
  const float di = dinv[i];
  float acc = di * di * h[i * W + t] + bias[t];
  const int beg = off[i], end = off[i + 1];
  int j = beg;
  for (; j + 4 <= end; j += 4) {
    int s0 = csr[j + 0], s1 = csr[j + 1], s2 = csr[j + 2], s3 = csr[j + 3];
    float w0 = dinv[s0] * di, w1 = dinv[s1] * di;
    float w2 = dinv[s2] * di, w3 = dinv[s3] * di;
    float v0 = h[s0 * W + t], v1 = h[s1 * W + t];
    float v2 = h[s2 * W + t], v3 = h[s3 * W + t];
    acc += w0 * v0 + w1 * v1 + w2 * v2 + w3 * v3;
  }
  for (; j < end; ++j) {
    int s = csr[j];
    acc += dinv[s] * di * h[s * W + t];
  }
  out[i * W + t] = acc;
}

// ---------------- BN stats ----------------
__global__ void bnstat_kernel(const float* __restrict__ a, int n, float* __restrict__ acc) {
  const int c = threadIdx.x & 127;
  const int half = threadIdx.x >> 7;
  const int rstart = blockIdx.x * 2 + half;
  const int rstep = gridDim.x * 2;
  float s = 0.f, ss = 0.f;
  for (int r = rstart; r < n; r += rstep) {
    float v = a[r * 128 + c];
    s += v;
    ss += v * v;
  }
  atomicAdd(&acc[c], s);
  atomicAdd(&acc[128 + c], ss);
}

__global__ void bnfin_kernel(const float* __restrict__ acc, const float* __restrict__ gamma,
                             const float* __restrict__ beta, int n, float* __restrict__ ss) {
  const int c = threadIdx.x;
  const float inv_n = 1.f / (float)n;
  const float mean = acc[c] * inv_n;
  const float var = acc[128 + c] * inv_n - mean * mean;
  const float sc = gamma[c] * rsqrtf(var + 1e-5f);
  ss[c] = sc;
  ss[128 + c] = beta[c] - mean * sc;
}

// ---------------- launch ----------------
extern "C" void kernel_launch(void* const* d_in, const int* in_sizes, int n_in,
                              void* d_out, int out_size, void* d_ws, size_t ws_size,
                              hipStream_t stream) {
  const float* x = (const float*)d_in[0];
  const int* ei = (const int*)d_in[1];
  const float* W1 = (const float*)d_in[2];
  const float* b1 = (const float*)d_in[3];
  const float* gamma = (const float*)d_in[4];
  const float* beta = (const float*)d_in[5];
  const float* W2 = (const float*)d_in[6];
  const float* b2 = (const float*)d_in[7];
  float* out = (float*)d_out;

  const int n = in_sizes[0] / 128;
  const int E = in_sizes[1] / 2;
  const int* src = ei;
  const int* dst = ei + E;

  // workspace carve (all within ws; ~117 MB total)
  char* p = (char*)d_ws;
  auto carve = [&](size_t bytes) {
    char* r = p;
    p += (bytes + 255) & ~(size_t)255;
    return r;
  };
  int* cnt = (int*)carve((size_t)n * 4);
  int* off = (int*)carve((size_t)(n + 1) * 4);
  int* cur = (int*)carve((size_t)n * 4);
  float* dinv = (float*)carve((size_t)n * 4);
  int* bsum = (int*)carve(1024 * 4);
  float* bnacc = (float*)carve(256 * 4);
  float* bnss = (float*)carve(256 * 4);
  int* csr = (int*)carve((size_t)E * 4);
  float* h1 = (float*)carve((size_t)n * 128 * 4);
  float* agg1 = (float*)carve((size_t)n * 128 * 4);
  float* h2 = h1;  // h1 dead after agg1; reuse for layer-2 GEMM output (n x 64)

  const int nb = (n + 255) / 256;

  zero_kernel<<<(n + 255) / 256, 256, 0, stream>>>(cnt, n, bnacc);
  count_kernel<<<(E + 255) / 256, 256, 0, stream>>>(dst, E, cnt);
  scan1_kernel<<<nb, 256, 0, stream>>>(cnt, n, bsum);
  scan2_kernel<<<1, 512, 0, stream>>>(bsum, nb);
  scan3_kernel<<<nb, 256, 0, stream>>>(cnt, n, bsum, off, cur, dinv, E);
  fill_kernel<<<(E + 255) / 256, 256, 0, stream>>>(src, dst, E, cur, csr);

  // conv1: h1 = x @ W1; agg1 = norm-agg(h1) + b1
  dim3 g1((n + 63) / 64, 2);
  gemm_kernel<false><<<g1, 256, 0, stream>>>(x, W1, h1, n, 128, nullptr, nullptr);
  agg_kernel<128><<<n, 128, 0, stream>>>(h1, dinv, off, csr, b1, agg1, n);

  // BN stats + finalize
  bnstat_kernel<<<512, 256, 0, stream>>>(agg1, n, bnacc);
  bnfin_kernel<<<1, 128, 0, stream>>>(bnacc, gamma, beta, n, bnss);

  // conv2: h2 = relu(bn(agg1)) @ W2 (BN+ReLU fused into A-load); out = norm-agg(h2) + b2
  dim3 g2((n + 63) / 64, 1);
  gemm_kernel<true><<<g2, 256, 0, stream>>>(agg1, W2, h2, n, 64, bnss, bnss + 128);
  agg_kernel<64><<<n, 64, 0, stream>>>(h2, dinv, off, csr, b2, out, n);
}